// Round 1
// baseline (2281.272 us; speedup 1.0000x reference)
//
#include <hip/hip_runtime.h>
#include <math.h>

// ---------------------------------------------------------------------------
// K1: fused conv1 (9x9, 1->256) + primary conv (per-depth 9x9 stride-2, 32->32)
// One block handles one (b, d) slice: conv1 channels c = i*8+d, i=0..31.
// Writes capsules in layout caps[b][e=d][n], n = oc*36 + w*6 + h.
// ---------------------------------------------------------------------------
#define IRS 404   // interm row stride per channel (floats): 404*4=1616B, 16B aligned, odd mod-32 bank stride

__global__ __launch_bounds__(256, 2) void k_conv(
    const float* __restrict__ x,    // [1024,1,28,28]
    const float* __restrict__ c1w,  // [256,1,9,9]
    const float* __restrict__ c1b,  // [256]
    const float* __restrict__ pw,   // [32,32,1,9,9]
    const float* __restrict__ pb,   // [32]
    float* __restrict__ caps)       // [1024,8,1152]
{
    __shared__ float img[784];          // 28x28 input image
    __shared__ float cw[32 * 81];       // conv1 weights for the 32 channels of this d
    __shared__ float interm[32 * IRS];  // conv1 output slice [32][20*20] (padded stride)
    __shared__ float w2[32 * 81];       // prim weights for current input channel i

    const int t = threadIdx.x;
    const int bd = blockIdx.x;
    const int b = bd >> 3, d = bd & 7;

    // ---- stage image (784 floats, coalesced float4) ----
    const float* xb = x + b * 784;
    for (int idx = t; idx < 196; idx += 256)
        ((float4*)img)[idx] = ((const float4*)xb)[idx];
    // ---- stage conv1 weights for channels i*8+d ----
    for (int idx = t; idx < 2592; idx += 256) {
        int i = idx / 81, k = idx - i * 81;
        cw[idx] = c1w[(i * 8 + d) * 81 + k];
    }
    __syncthreads();

    // ---- phase 1: conv1, 32 channels x 20x20 ----
    {
        const int ch = t & 31, ys = t >> 5;   // ys in 0..7
        const float bias = c1b[ch * 8 + d];
        for (int y = ys; y < 20; y += 8) {
            float acc[20];
#pragma unroll
            for (int xx = 0; xx < 20; ++xx) acc[xx] = bias;
#pragma unroll
            for (int ky = 0; ky < 9; ++ky) {
                float r[28];
                const float* row = img + (y + ky) * 28;
#pragma unroll
                for (int q = 0; q < 7; ++q) {
                    float4 v = ((const float4*)row)[q];
                    r[q * 4 + 0] = v.x; r[q * 4 + 1] = v.y;
                    r[q * 4 + 2] = v.z; r[q * 4 + 3] = v.w;
                }
#pragma unroll
                for (int kx = 0; kx < 9; ++kx) {
                    float w = cw[ch * 81 + ky * 9 + kx];
#pragma unroll
                    for (int xx = 0; xx < 20; ++xx)
                        acc[xx] += r[xx + kx] * w;
                }
            }
            float* orow = interm + ch * IRS + y * 20;
#pragma unroll
            for (int q = 0; q < 5; ++q) {
                float4 v;
                v.x = fmaxf(acc[q * 4 + 0], 0.f);
                v.y = fmaxf(acc[q * 4 + 1], 0.f);
                v.z = fmaxf(acc[q * 4 + 2], 0.f);
                v.w = fmaxf(acc[q * 4 + 3], 0.f);
                ((float4*)orow)[q] = v;
            }
        }
    }
    __syncthreads();

    // ---- phase 2: primary conv (stride 2), output [32 oc][6 h][6 w] ----
    const int oc = t & 31, yh = t >> 5;   // yh 0..7, active if < 6
    float acc[6];
#pragma unroll
    for (int w = 0; w < 6; ++w) acc[w] = pb[oc];

    for (int i = 0; i < 32; ++i) {
        __syncthreads();  // protect w2 from previous-iteration readers
        for (int idx = t; idx < 2592; idx += 256) {
            int o2 = idx / 81, k = idx - o2 * 81;
            w2[idx] = pw[o2 * 2592 + i * 81 + k];
        }
        __syncthreads();
        if (yh < 6) {
#pragma unroll
            for (int ky = 0; ky < 9; ++ky) {
                const float* row = interm + i * IRS + (2 * yh + ky) * 20;
                float r[20];
#pragma unroll
                for (int q = 0; q < 5; ++q) {
                    float4 v = ((const float4*)row)[q];
                    r[q * 4 + 0] = v.x; r[q * 4 + 1] = v.y;
                    r[q * 4 + 2] = v.z; r[q * 4 + 3] = v.w;
                }
#pragma unroll
                for (int kx = 0; kx < 9; ++kx) {
                    float w = w2[oc * 81 + ky * 9 + kx];
#pragma unroll
                    for (int xw = 0; xw < 6; ++xw)
                        acc[xw] += r[2 * xw + kx] * w;
                }
            }
        }
    }
    if (yh < 6) {
        float* cp = caps + (b * 8 + d) * 1152;
#pragma unroll
        for (int xw = 0; xw < 6; ++xw)
            cp[oc * 36 + xw * 6 + yh] = fmaxf(acc[xw], 0.f);
    }
}

// ---------------------------------------------------------------------------
// K2: per-b block: u = caps @ dig_W + dig_Wb, 3 routing iterations fully in
// LDS, then output head + softmax.  u kept transposed [16][RS_U] for
// conflict-free s-accumulation reads.
// ---------------------------------------------------------------------------
#define RS_U 1154
#define RS_C 580

__global__ __launch_bounds__(256, 1) void k_route(
    const float* __restrict__ caps,  // [1024,8,1152]
    const float* __restrict__ W,     // [1152,8,16]
    const float* __restrict__ Wb,    // [1152,16]
    const float* __restrict__ ow,    // [10,10,16,1]
    const float* __restrict__ ob,    // [10]
    float* __restrict__ out)         // [1024,10]
{
    __shared__ float u[16 * RS_U];     // 73,856 B  (u[f][n])
    __shared__ float blog[10 * 1152];  // 46,080 B  (routing logits b[j][n])
    __shared__ float chalf[10 * RS_C]; // 23,200 B  (softmax c for half the n's)
    __shared__ float vv[160];          // v[f][j]
    __shared__ float ss[160];          // s[j][f]
    __shared__ float red[16];          // logits scratch

    const int t = threadIdx.x;
    const int b = blockIdx.x;

    // ---- stage A: u[f][n] = sum_e caps[b,e,n] * W[n,e,f] + Wb[n,f] ----
    for (int n = t; n < 1152; n += 256) {
        float cv[8];
#pragma unroll
        for (int e = 0; e < 8; ++e) cv[e] = caps[(b * 8 + e) * 1152 + n];
#pragma unroll
        for (int fq = 0; fq < 4; ++fq) {
            float4 a4 = ((const float4*)(Wb + n * 16))[fq];
#pragma unroll
            for (int e = 0; e < 8; ++e) {
                float4 w4 = ((const float4*)(W + n * 128 + e * 16))[fq];
                a4.x += cv[e] * w4.x; a4.y += cv[e] * w4.y;
                a4.z += cv[e] * w4.z; a4.w += cv[e] * w4.w;
            }
            u[(fq * 4 + 0) * RS_U + n] = a4.x;
            u[(fq * 4 + 1) * RS_U + n] = a4.y;
            u[(fq * 4 + 2) * RS_U + n] = a4.z;
            u[(fq * 4 + 3) * RS_U + n] = a4.w;
        }
    }
    for (int idx = t; idx < 11520; idx += 256) blog[idx] = 0.f;
    __syncthreads();

    const int j = t >> 4, f = t & 15;  // for the (j,f) stages, active when t<160

    for (int iter = 0; iter < 3; ++iter) {
        float sacc = 0.f;
        for (int h = 0; h < 2; ++h) {
            // ---- stage B: c = softmax_j(blog) for n in [h*576, h*576+576) ----
            for (int idx = t; idx < 576; idx += 256) {
                int n = h * 576 + idx;
                float bv[10], m = -1e30f;
#pragma unroll
                for (int jj = 0; jj < 10; ++jj) {
                    bv[jj] = blog[jj * 1152 + n];
                    m = fmaxf(m, bv[jj]);
                }
                float sum = 0.f;
#pragma unroll
                for (int jj = 0; jj < 10; ++jj) { bv[jj] = __expf(bv[jj] - m); sum += bv[jj]; }
                float inv = 1.f / sum;
#pragma unroll
                for (int jj = 0; jj < 10; ++jj) chalf[jj * RS_C + idx] = bv[jj] * inv;
            }
            __syncthreads();
            // ---- stage C: s[j][f] += sum_n c[j][n] * u[f][n] ----
            if (t < 160) {
                const float* crow = chalf + j * RS_C;
                const float* urow = u + f * RS_U + h * 576;
#pragma unroll 8
                for (int m2 = 0; m2 < 576; ++m2)
                    sacc += crow[m2] * urow[m2];
            }
            __syncthreads();  // before next half overwrites chalf
        }
        if (t < 160) ss[j * 16 + f] = sacc;
        __syncthreads();
        // ---- stage D: squash (norms over the 10-class dim) -> v[f][j] ----
        if (t < 16) {
            float l2 = 0.f, l1 = 0.f;
#pragma unroll
            for (int jj = 0; jj < 10; ++jj) {
                float sv = ss[jj * 16 + t];
                l2 += sv * sv; l1 += fabsf(sv);
            }
            l2 = sqrtf(l2);
            float scale = l2 / (1.f + l2) / l1;
#pragma unroll
            for (int jj = 0; jj < 10; ++jj) vv[t * 10 + jj] = ss[jj * 16 + t] * scale;
        }
        __syncthreads();
        // ---- stage E: blog[j][n] += sum_f u[f][n] * v[f][j] ----
        if (iter < 2) {
            for (int n = t; n < 1152; n += 256) {
                float a[10];
#pragma unroll
                for (int jj = 0; jj < 10; ++jj) a[jj] = 0.f;
#pragma unroll
                for (int ff = 0; ff < 16; ++ff) {
                    float uf = u[ff * RS_U + n];
#pragma unroll
                    for (int jj = 0; jj < 10; ++jj) a[jj] += uf * vv[ff * 10 + jj];
                }
#pragma unroll
                for (int jj = 0; jj < 10; ++jj) blog[jj * 1152 + n] += a[jj];
            }
        }
        __syncthreads();
    }

    // ---- output head: logits[o] = sum_{i,f} v[f][i]*ow[o,i,f] + ob[o]; softmax ----
    if (t < 10) {
        float l = ob[t];
#pragma unroll
        for (int i2 = 0; i2 < 10; ++i2)
#pragma unroll
            for (int ff = 0; ff < 16; ++ff)
                l += vv[ff * 10 + i2] * ow[t * 160 + i2 * 16 + ff];
        red[t] = l;
    }
    __syncthreads();
    if (t == 0) {
        float m = -1e30f;
        for (int o = 0; o < 10; ++o) m = fmaxf(m, red[o]);
        float sum = 0.f; float e[10];
        for (int o = 0; o < 10; ++o) { e[o] = __expf(red[o] - m); sum += e[o]; }
        float inv = 1.f / sum;
        for (int o = 0; o < 10; ++o) out[b * 10 + o] = e[o] * inv;
    }
}

extern "C" void kernel_launch(void* const* d_in, const int* in_sizes, int n_in,
                              void* d_out, int out_size, void* d_ws, size_t ws_size,
                              hipStream_t stream) {
    const float* x     = (const float*)d_in[0];
    const float* c1w   = (const float*)d_in[1];
    const float* c1b   = (const float*)d_in[2];
    const float* pw    = (const float*)d_in[3];
    const float* pb    = (const float*)d_in[4];
    const float* digW  = (const float*)d_in[5];
    const float* digWb = (const float*)d_in[6];
    const float* outw  = (const float*)d_in[7];
    const float* outb  = (const float*)d_in[8];
    float* out = (float*)d_out;

    float* caps = (float*)d_ws;  // [1024][8][1152] = 37.75 MB

    k_conv<<<dim3(8192), dim3(256), 0, stream>>>(x, c1w, c1b, pw, pb, caps);
    k_route<<<dim3(1024), dim3(256), 0, stream>>>(caps, digW, digWb, outw, outb, out);
}

// Round 2
// 463.543 us; speedup vs baseline: 4.9214x; 4.9214x over previous
//
#include <hip/hip_runtime.h>
#include <math.h>

typedef __attribute__((ext_vector_type(8))) short bf16x8;
typedef __attribute__((ext_vector_type(4))) float f32x4;
#define MFMA16(a, b, c) __builtin_amdgcn_mfma_f32_16x16x32_bf16(a, b, c, 0, 0, 0)

__device__ __forceinline__ unsigned short f2bf(float x) {
    unsigned u = __builtin_bit_cast(unsigned, x);
    unsigned r = (u + 0x7fffu + ((u >> 16) & 1u)) >> 16;   // RNE
    return (unsigned short)r;
}

// ws layout (bytes):
//   [0, 37748736)             caps  f32 [1024][8][1152]
//   [37748736, +49152)        A1f   bf16 frag: [(d*2+m)*3+k3][lane][e]   (conv1 weights)
//   [37797888, +196608)       A2f   bf16 frag: [(i*3+k3)*2+m][lane][e]   (prim weights)
#define CAPS_BYTES 37748736
#define A1F_ELEMS  24576
#define A2F_ELEMS  98304

// ---------------------------------------------------------------------------
// K0: pack conv weights into MFMA fragment layout (bf16), zero-padded K.
// k-mapping (both A and B everywhere): k = k3*32 + (lane>>4)*8 + e
// ---------------------------------------------------------------------------
__global__ void k_prep(const float* __restrict__ c1w,  // [256,1,9,9]
                       const float* __restrict__ pw,   // [32,32,1,9,9]
                       unsigned short* __restrict__ w1f,
                       unsigned short* __restrict__ w2f)
{
    int idx = blockIdx.x * 256 + threadIdx.x;
    if (idx < A1F_ELEMS) {
        int e = idx & 7, lane = (idx >> 3) & 63, f = idx >> 9;
        int k3 = f % 3, m = (f / 3) & 1, d = f / 6;
        int ch = (lane & 15) + m * 16;                  // local channel i
        int k = k3 * 32 + ((lane >> 4) << 3) + e;
        float v = (k < 81) ? c1w[(ch * 8 + d) * 81 + k] : 0.f;
        w1f[idx] = f2bf(v);
    } else if (idx < A1F_ELEMS + A2F_ELEMS) {
        int j = idx - A1F_ELEMS;
        int e = j & 7, lane = (j >> 3) & 63, f = j >> 9;
        int m = f & 1, k3 = (f >> 1) % 3, i = f / 6;
        int oc = (lane & 15) + m * 16;
        int kk = k3 * 32 + ((lane >> 4) << 3) + e;
        float v = (kk < 81) ? pw[oc * 2592 + i * 81 + kk] : 0.f;
        w2f[j] = f2bf(v);
    }
}

// ---------------------------------------------------------------------------
// K1: fused conv1 + prim conv via bf16 MFMA, one block per (b,d) slice.
// Phase 1: conv1 GEMM M=32(2 tiles) N=400(25 tiles) K=96  -> interm bf16 [32][400]
// Phase 2: prim  GEMM M=32(2 tiles) N=48(3 tiles,36 valid) K=32i*96, K-split by wave
// ---------------------------------------------------------------------------
#define RS2 408   // interm row stride (bf16 elems)

__global__ __launch_bounds__(256) void k_conv(
    const float* __restrict__ x,    // [1024,1,28,28]
    const float* __restrict__ c1b,  // [256]
    const float* __restrict__ pb,   // [32]
    const unsigned short* __restrict__ w1f,
    const unsigned short* __restrict__ w2f,
    float* __restrict__ caps)       // [1024,8,1152]
{
    __shared__ unsigned short img_bf[800];
    __shared__ int offk1[96], offk2[96];
    __shared__ __align__(16) unsigned short interm[32 * RS2];  // 26112 B; aliased as red f32 in epilogue

    const int t = threadIdx.x;
    const int lane = t & 63, w = t >> 6;
    const int g = lane >> 4, col = lane & 15;
    const int b = blockIdx.x >> 3, d = blockIdx.x & 7;

    // ---- stage image (bf16) + k->offset tables ----
    for (int idx = t; idx < 784; idx += 256) img_bf[idx] = f2bf(x[b * 784 + idx]);
    if (t < 96) {
        int ky = t / 9, kx = t - ky * 9;
        offk1[t] = (t < 81) ? ky * 28 + kx : 0;   // pad -> safe dummy (A side is zero)
        offk2[t] = (t < 81) ? ky * 20 + kx : 0;
    }
    __syncthreads();

    // =================== phase 1: conv1 ===================
    {
        bf16x8 a1[2][3];
        const bf16x8* w1p = (const bf16x8*)w1f;
#pragma unroll
        for (int m = 0; m < 2; ++m)
#pragma unroll
            for (int k3 = 0; k3 < 3; ++k3)
                a1[m][k3] = w1p[((d * 2 + m) * 3 + k3) * 64 + lane];

        float bias[2][4];
#pragma unroll
        for (int m = 0; m < 2; ++m)
#pragma unroll
            for (int r = 0; r < 4; ++r)
                bias[m][r] = c1b[(m * 16 + g * 4 + r) * 8 + d];

        int o1[3][8];
#pragma unroll
        for (int k3 = 0; k3 < 3; ++k3)
#pragma unroll
            for (int e = 0; e < 8; ++e)
                o1[k3][e] = offk1[k3 * 32 + g * 8 + e];

        for (int nt = w; nt < 25; nt += 4) {
            int p = nt * 16 + col;
            int py = p / 20;
            int base = py * 28 + (p - py * 20);
            bf16x8 bf[3];
#pragma unroll
            for (int k3 = 0; k3 < 3; ++k3) {
                bf16x8 bb;
#pragma unroll
                for (int e = 0; e < 8; ++e)
                    bb[e] = (short)img_bf[base + o1[k3][e]];
                bf[k3] = bb;
            }
            f32x4 acc0 = {0.f, 0.f, 0.f, 0.f};
            f32x4 acc1 = {0.f, 0.f, 0.f, 0.f};
#pragma unroll
            for (int k3 = 0; k3 < 3; ++k3) {
                acc0 = MFMA16(a1[0][k3], bf[k3], acc0);
                acc1 = MFMA16(a1[1][k3], bf[k3], acc1);
            }
#pragma unroll
            for (int r = 0; r < 4; ++r) {
                int row = g * 4 + r;
                interm[row * RS2 + p]        = f2bf(fmaxf(acc0[r] + bias[0][r], 0.f));
                interm[(16 + row) * RS2 + p] = f2bf(fmaxf(acc1[r] + bias[1][r], 0.f));
            }
        }
    }
    __syncthreads();

    // =================== phase 2: prim conv (K-split by wave) ===================
    f32x4 acc[2][3];
#pragma unroll
    for (int m = 0; m < 2; ++m)
#pragma unroll
        for (int nt = 0; nt < 3; ++nt)
            acc[m][nt] = (f32x4){0.f, 0.f, 0.f, 0.f};
    {
        int o2[3][8];
#pragma unroll
        for (int k3 = 0; k3 < 3; ++k3)
#pragma unroll
            for (int e = 0; e < 8; ++e)
                o2[k3][e] = offk2[k3 * 32 + g * 8 + e];

        int base2[3];
#pragma unroll
        for (int nt = 0; nt < 3; ++nt) {
            int p2 = nt * 16 + col;
            int xw = p2 / 6, yh = p2 - xw * 6;
            base2[nt] = yh * 40 + xw * 2;   // (2*yh)*20 + 2*xw
        }

        const bf16x8* w2p = (const bf16x8*)w2f;
        for (int i = w * 8; i < w * 8 + 8; ++i) {
            int ib = i * RS2;
#pragma unroll
            for (int k3 = 0; k3 < 3; ++k3) {
                bf16x8 a0 = w2p[((i * 3 + k3) * 2 + 0) * 64 + lane];
                bf16x8 a1v = w2p[((i * 3 + k3) * 2 + 1) * 64 + lane];
                bf16x8 bb[3];
#pragma unroll
                for (int nt = 0; nt < 3; ++nt) {
                    bf16x8 v;
#pragma unroll
                    for (int e = 0; e < 8; ++e)
                        v[e] = (short)interm[ib + base2[nt] + o2[k3][e]];
                    bb[nt] = v;
                }
#pragma unroll
                for (int nt = 0; nt < 3; ++nt) {
                    acc[0][nt] = MFMA16(a0, bb[nt], acc[0][nt]);
                    acc[1][nt] = MFMA16(a1v, bb[nt], acc[1][nt]);
                }
            }
        }
    }
    __syncthreads();                 // everyone done reading interm
    // ---- cross-wave reduction in LDS (overlays interm) ----
    float* red = (float*)interm;     // 4 waves * 6 tiles * 64 lanes * 4 f32 = 24576 B
    {
        f32x4* rp = (f32x4*)red;
#pragma unroll
        for (int m = 0; m < 2; ++m)
#pragma unroll
            for (int nt = 0; nt < 3; ++nt)
                rp[(w * 6 + m * 3 + nt) * 64 + lane] = acc[m][nt];
    }
    __syncthreads();
    {
        const f32x4* rp = (const f32x4*)red;
        for (int idx = t; idx < 384; idx += 256) {
            int tile = idx >> 6, ls = idx & 63;
            f32x4 s = rp[tile * 64 + ls];
#pragma unroll
            for (int w2 = 1; w2 < 4; ++w2)
                s += rp[(w2 * 6 + tile) * 64 + ls];
            int m = tile / 3, nt = tile - m * 3;
            int p2 = nt * 16 + (ls & 15);
            if (p2 < 36) {
                int gr = ls >> 4;
#pragma unroll
                for (int r = 0; r < 4; ++r) {
                    int oc = m * 16 + gr * 4 + r;
                    caps[(b * 8 + d) * 1152 + oc * 36 + p2] = fmaxf(s[r] + pb[oc], 0.f);
                }
            }
        }
    }
}

// ---------------------------------------------------------------------------
// K2: routing (unchanged from passing R1 version)
// ---------------------------------------------------------------------------
#define RS_U 1154
#define RS_C 580

__global__ __launch_bounds__(256, 1) void k_route(
    const float* __restrict__ caps,  // [1024,8,1152]
    const float* __restrict__ W,     // [1152,8,16]
    const float* __restrict__ Wb,    // [1152,16]
    const float* __restrict__ ow,    // [10,10,16,1]
    const float* __restrict__ ob,    // [10]
    float* __restrict__ out)         // [1024,10]
{
    __shared__ float u[16 * RS_U];
    __shared__ float blog[10 * 1152];
    __shared__ float chalf[10 * RS_C];
    __shared__ float vv[160];
    __shared__ float ss[160];
    __shared__ float red[16];

    const int t = threadIdx.x;
    const int b = blockIdx.x;

    for (int n = t; n < 1152; n += 256) {
        float cv[8];
#pragma unroll
        for (int e = 0; e < 8; ++e) cv[e] = caps[(b * 8 + e) * 1152 + n];
#pragma unroll
        for (int fq = 0; fq < 4; ++fq) {
            float4 a4 = ((const float4*)(Wb + n * 16))[fq];
#pragma unroll
            for (int e = 0; e < 8; ++e) {
                float4 w4 = ((const float4*)(W + n * 128 + e * 16))[fq];
                a4.x += cv[e] * w4.x; a4.y += cv[e] * w4.y;
                a4.z += cv[e] * w4.z; a4.w += cv[e] * w4.w;
            }
            u[(fq * 4 + 0) * RS_U + n] = a4.x;
            u[(fq * 4 + 1) * RS_U + n] = a4.y;
            u[(fq * 4 + 2) * RS_U + n] = a4.z;
            u[(fq * 4 + 3) * RS_U + n] = a4.w;
        }
    }
    for (int idx = t; idx < 11520; idx += 256) blog[idx] = 0.f;
    __syncthreads();

    const int j = t >> 4, f = t & 15;

    for (int iter = 0; iter < 3; ++iter) {
        float sacc = 0.f;
        for (int h = 0; h < 2; ++h) {
            for (int idx = t; idx < 576; idx += 256) {
                int n = h * 576 + idx;
                float bv[10], m = -1e30f;
#pragma unroll
                for (int jj = 0; jj < 10; ++jj) {
                    bv[jj] = blog[jj * 1152 + n];
                    m = fmaxf(m, bv[jj]);
                }
                float sum = 0.f;
#pragma unroll
                for (int jj = 0; jj < 10; ++jj) { bv[jj] = __expf(bv[jj] - m); sum += bv[jj]; }
                float inv = 1.f / sum;
#pragma unroll
                for (int jj = 0; jj < 10; ++jj) chalf[jj * RS_C + idx] = bv[jj] * inv;
            }
            __syncthreads();
            if (t < 160) {
                const float* crow = chalf + j * RS_C;
                const float* urow = u + f * RS_U + h * 576;
#pragma unroll 8
                for (int m2 = 0; m2 < 576; ++m2)
                    sacc += crow[m2] * urow[m2];
            }
            __syncthreads();
        }
        if (t < 160) ss[j * 16 + f] = sacc;
        __syncthreads();
        if (t < 16) {
            float l2 = 0.f, l1 = 0.f;
#pragma unroll
            for (int jj = 0; jj < 10; ++jj) {
                float sv = ss[jj * 16 + t];
                l2 += sv * sv; l1 += fabsf(sv);
            }
            l2 = sqrtf(l2);
            float scale = l2 / (1.f + l2) / l1;
#pragma unroll
            for (int jj = 0; jj < 10; ++jj) vv[t * 10 + jj] = ss[jj * 16 + t] * scale;
        }
        __syncthreads();
        if (iter < 2) {
            for (int n = t; n < 1152; n += 256) {
                float a[10];
#pragma unroll
                for (int jj = 0; jj < 10; ++jj) a[jj] = 0.f;
#pragma unroll
                for (int ff = 0; ff < 16; ++ff) {
                    float uf = u[ff * RS_U + n];
#pragma unroll
                    for (int jj = 0; jj < 10; ++jj) a[jj] += uf * vv[ff * 10 + jj];
                }
#pragma unroll
                for (int jj = 0; jj < 10; ++jj) blog[jj * 1152 + n] += a[jj];
            }
        }
        __syncthreads();
    }

    if (t < 10) {
        float l = ob[t];
#pragma unroll
        for (int i2 = 0; i2 < 10; ++i2)
#pragma unroll
            for (int ff = 0; ff < 16; ++ff)
                l += vv[ff * 10 + i2] * ow[t * 160 + i2 * 16 + ff];
        red[t] = l;
    }
    __syncthreads();
    if (t == 0) {
        float m = -1e30f;
        for (int o = 0; o < 10; ++o) m = fmaxf(m, red[o]);
        float sum = 0.f; float e[10];
        for (int o = 0; o < 10; ++o) { e[o] = __expf(red[o] - m); sum += e[o]; }
        float inv = 1.f / sum;
        for (int o = 0; o < 10; ++o) out[b * 10 + o] = e[o] * inv;
    }
}

extern "C" void kernel_launch(void* const* d_in, const int* in_sizes, int n_in,
                              void* d_out, int out_size, void* d_ws, size_t ws_size,
                              hipStream_t stream) {
    const float* x     = (const float*)d_in[0];
    const float* c1w   = (const float*)d_in[1];
    const float* c1b   = (const float*)d_in[2];
    const float* pw    = (const float*)d_in[3];
    const float* pb    = (const float*)d_in[4];
    const float* digW  = (const float*)d_in[5];
    const float* digWb = (const float*)d_in[6];
    const float* outw  = (const float*)d_in[7];
    const float* outb  = (const float*)d_in[8];
    float* out = (float*)d_out;

    float* caps = (float*)d_ws;
    unsigned short* w1f = (unsigned short*)((char*)d_ws + CAPS_BYTES);
    unsigned short* w2f = w1f + A1F_ELEMS;

    k_prep<<<dim3(480), dim3(256), 0, stream>>>(c1w, pw, w1f, w2f);
    k_conv<<<dim3(8192), dim3(256), 0, stream>>>(x, c1b, pb, w1f, w2f, caps);
    k_route<<<dim3(1024), dim3(256), 0, stream>>>(caps, digW, digWb, outw, outb, out);
}

// Round 3
// 352.966 us; speedup vs baseline: 6.4631x; 1.3133x over previous
//
#include <hip/hip_runtime.h>
#include <math.h>

typedef __attribute__((ext_vector_type(8))) short bf16x8;
typedef __attribute__((ext_vector_type(4))) float f32x4;
#define MFMA16(a, b, c) __builtin_amdgcn_mfma_f32_16x16x32_bf16(a, b, c, 0, 0, 0)

union U8 { bf16x8 v; int i4[4]; };

__device__ __forceinline__ unsigned short f2bf(float x) {
    unsigned u = __builtin_bit_cast(unsigned, x);
    unsigned r = (u + 0x7fffu + ((u >> 16) & 1u)) >> 16;   // RNE
    return (unsigned short)r;
}

// K-permutation sigma (same for A and B everywhere, so it cancels in the GEMM):
// kidx = grp*8+e, grp = k3*4+g.
//   grp 0..8 : (ky=grp, kx=e)        -> contiguous row pairs
//   grp 9    : (ky=e,  kx=8)         -> the 9th column
//   grp 10   : e==0 -> (8,8), else pad
//   grp 11   : pad
__device__ __forceinline__ int koff_of(int kidx) {
    int grp = kidx >> 3, e = kidx & 7;
    if (grp < 9)  return grp * 9 + e;
    if (grp == 9) return e * 9 + 8;
    if (grp == 10) return (e == 0) ? 80 : -1;
    return -1;
}

#define CAPS_BYTES 37748736
#define A1F_ELEMS  24576
#define A2F_ELEMS  98304

__global__ void k_prep(const float* __restrict__ c1w,  // [256,1,9,9]
                       const float* __restrict__ pw,   // [32,32,1,9,9]
                       unsigned short* __restrict__ w1f,
                       unsigned short* __restrict__ w2f)
{
    int idx = blockIdx.x * 256 + threadIdx.x;
    if (idx < A1F_ELEMS) {
        int e = idx & 7, lane = (idx >> 3) & 63, f = idx >> 9;
        int k3 = f % 3, m = (f / 3) & 1, d = f / 6;
        int ch = (lane & 15) + m * 16;
        int kidx = k3 * 32 + ((lane >> 4) << 3) + e;
        int ko = koff_of(kidx);
        w1f[idx] = f2bf(ko >= 0 ? c1w[(ch * 8 + d) * 81 + ko] : 0.f);
    } else if (idx < A1F_ELEMS + A2F_ELEMS) {
        int j = idx - A1F_ELEMS;
        int e = j & 7, lane = (j >> 3) & 63, f = j >> 9;
        int m = f & 1, k3 = (f >> 1) % 3, i = f / 6;
        int oc = (lane & 15) + m * 16;
        int kidx = k3 * 32 + ((lane >> 4) << 3) + e;
        int ko = koff_of(kidx);
        w2f[j] = f2bf(ko >= 0 ? pw[oc * 2592 + i * 81 + ko] : 0.f);
    }
}

// ---------------------------------------------------------------------------
// K1: fused conv1 + prim conv, bf16 MFMA. One block = (b-pair, d).
// ---------------------------------------------------------------------------
#define RS2 408   // interm row stride (bf16 elems), even

__global__ __launch_bounds__(256, 2) void k_conv(
    const float* __restrict__ x,    // [1024,1,28,28]
    const float* __restrict__ c1b,  // [256]
    const float* __restrict__ pb,   // [32]
    const unsigned short* __restrict__ w1f,
    const unsigned short* __restrict__ w2f,
    float* __restrict__ caps)       // [1024,8,1152]
{
    __shared__ __align__(16) unsigned short img[2][800];
    __shared__ __align__(16) unsigned short imgs[2][800];   // shifted by 1 elem
    __shared__ __align__(16) unsigned short interm[2][32 * RS2]; // 52224 B; f32 red overlay later

    const int t = threadIdx.x;
    const int lane = t & 63, w = t >> 6;
    const int g = lane >> 4, col = lane & 15;
    const int bp = blockIdx.x >> 3, d = blockIdx.x & 7;
    const int b0 = bp * 2;

    // ---- stage images (bf16) + shifted copies ----
    for (int idx = t; idx < 1568; idx += 256) {
        int bb = idx >= 784, j = idx - bb * 784;
        unsigned short v = f2bf(x[(b0 + bb) * 784 + j]);
        img[bb][j] = v;
        if (j > 0) imgs[bb][j - 1] = v;
    }
    __syncthreads();

    // =================== phase 1: conv1 (50 tiles: 2 b x 25) ===================
    {
        bf16x8 a1[2][3];
        const bf16x8* w1p = (const bf16x8*)w1f;
#pragma unroll
        for (int m = 0; m < 2; ++m)
#pragma unroll
            for (int k3 = 0; k3 < 3; ++k3)
                a1[m][k3] = w1p[((d * 2 + m) * 3 + k3) * 64 + lane];

        float bias[2][4];
#pragma unroll
        for (int m = 0; m < 2; ++m)
#pragma unroll
            for (int r = 0; r < 4; ++r)
                bias[m][r] = c1b[(m * 16 + g * 4 + r) * 8 + d];

        for (int q = w; q < 50; q += 4) {
            int bb = q >= 25, nt = q - bb * 25;
            int p = nt * 16 + col;
            int py = p / 20, px = p - py * 20;
            int base = py * 28 + px;
            const unsigned short* imgp = &img[bb][0];
            const unsigned short* rbase = (base & 1) ? &imgs[bb][base - 1] : &img[bb][base];

            bf16x8 bfrag[3];
#pragma unroll
            for (int k3 = 0; k3 < 2; ++k3) {
                int grp = k3 * 4 + g;
                U8 u8;
#pragma unroll
                for (int qq = 0; qq < 4; ++qq)
                    u8.i4[qq] = *(const int*)(rbase + grp * 28 + 2 * qq);
                bfrag[k3] = u8.v;
            }
            {
                U8 u8;
                if (g == 0) {
#pragma unroll
                    for (int qq = 0; qq < 4; ++qq)
                        u8.i4[qq] = *(const int*)(rbase + 8 * 28 + 2 * qq);
                } else if (g == 1) {
#pragma unroll
                    for (int e = 0; e < 8; ++e)
                        u8.v[e] = (short)imgp[base + e * 28 + 8];
                } else if (g == 2) {
                    u8.i4[0] = u8.i4[1] = u8.i4[2] = u8.i4[3] = 0;
                    u8.v[0] = (short)imgp[base + 8 * 28 + 8];
                } else {
                    u8.i4[0] = u8.i4[1] = u8.i4[2] = u8.i4[3] = 0;
                }
                bfrag[2] = u8.v;
            }

            f32x4 acc0 = {0.f, 0.f, 0.f, 0.f};
            f32x4 acc1 = {0.f, 0.f, 0.f, 0.f};
#pragma unroll
            for (int k3 = 0; k3 < 3; ++k3) {
                acc0 = MFMA16(a1[0][k3], bfrag[k3], acc0);
                acc1 = MFMA16(a1[1][k3], bfrag[k3], acc1);
            }
#pragma unroll
            for (int r = 0; r < 4; ++r) {
                int row = g * 4 + r;
                interm[bb][row * RS2 + p]        = f2bf(fmaxf(acc0[r] + bias[0][r], 0.f));
                interm[bb][(16 + row) * RS2 + p] = f2bf(fmaxf(acc1[r] + bias[1][r], 0.f));
            }
        }
    }
    __syncthreads();

    // =================== phase 2: prim conv, K-split by wave ===================
    f32x4 acc[2][2][3];
#pragma unroll
    for (int bb = 0; bb < 2; ++bb)
#pragma unroll
        for (int m = 0; m < 2; ++m)
#pragma unroll
            for (int nt = 0; nt < 3; ++nt)
                acc[bb][m][nt] = (f32x4){0.f, 0.f, 0.f, 0.f};
    {
        int base2[3];
#pragma unroll
        for (int nt = 0; nt < 3; ++nt) {
            int p2 = nt * 16 + col;
            int xw = p2 / 6, yh = p2 - xw * 6;
            base2[nt] = yh * 40 + xw * 2;
        }
        const bf16x8* w2p = (const bf16x8*)w2f;
        for (int i = w * 8; i < w * 8 + 8; ++i) {
#pragma unroll
            for (int k3 = 0; k3 < 3; ++k3) {
                bf16x8 a0  = w2p[((i * 3 + k3) * 2 + 0) * 64 + lane];
                bf16x8 a1v = w2p[((i * 3 + k3) * 2 + 1) * 64 + lane];
#pragma unroll
                for (int bb = 0; bb < 2; ++bb) {
                    const unsigned short* ib0 = &interm[bb][0] + i * RS2;
#pragma unroll
                    for (int nt = 0; nt < 3; ++nt) {
                        const unsigned short* ibase = ib0 + base2[nt];
                        U8 u8;
                        if (k3 < 2) {
                            int grp = k3 * 4 + g;
#pragma unroll
                            for (int qq = 0; qq < 4; ++qq)
                                u8.i4[qq] = *(const int*)(ibase + grp * 20 + 2 * qq);
                        } else if (g == 0) {
#pragma unroll
                            for (int qq = 0; qq < 4; ++qq)
                                u8.i4[qq] = *(const int*)(ibase + 160 + 2 * qq);
                        } else if (g == 1) {
#pragma unroll
                            for (int e = 0; e < 8; ++e)
                                u8.v[e] = (short)ibase[e * 20 + 8];
                        } else if (g == 2) {
                            u8.i4[0] = u8.i4[1] = u8.i4[2] = u8.i4[3] = 0;
                            u8.v[0] = (short)ibase[168];
                        } else {
                            u8.i4[0] = u8.i4[1] = u8.i4[2] = u8.i4[3] = 0;
                        }
                        acc[bb][0][nt] = MFMA16(a0,  u8.v, acc[bb][0][nt]);
                        acc[bb][1][nt] = MFMA16(a1v, u8.v, acc[bb][1][nt]);
                    }
                }
            }
        }
    }
    __syncthreads();                 // all interm reads done
    // ---- cross-wave reduction (f32 overlay on interm) ----
    f32x4* rp = (f32x4*)&interm[0][0];   // [w][bb][m*3+nt][lane] : 4*2*6*64 = 49152 B
    {
#pragma unroll
        for (int bb = 0; bb < 2; ++bb)
#pragma unroll
            for (int m = 0; m < 2; ++m)
#pragma unroll
                for (int nt = 0; nt < 3; ++nt)
                    rp[(((w * 2 + bb) * 6) + m * 3 + nt) * 64 + lane] = acc[bb][m][nt];
    }
    __syncthreads();
    for (int idx = t; idx < 768; idx += 256) {
        int bb = idx / 384, r2 = idx - bb * 384;
        int tile = r2 >> 6, ls = r2 & 63;
        f32x4 s = rp[((0 * 2 + bb) * 6 + tile) * 64 + ls];
#pragma unroll
        for (int ww = 1; ww < 4; ++ww)
            s += rp[((ww * 2 + bb) * 6 + tile) * 64 + ls];
        int m = tile / 3, nt = tile - m * 3;
        int p2 = nt * 16 + (ls & 15);
        if (p2 < 36) {
            int gr = ls >> 4;
#pragma unroll
            for (int r = 0; r < 4; ++r) {
                int oc = m * 16 + gr * 4 + r;
                caps[((b0 + bb) * 8 + d) * 1152 + oc * 36 + p2] = fmaxf(s[r] + pb[oc], 0.f);
            }
        }
    }
}

// ---------------------------------------------------------------------------
// K2: routing, 512 threads, vectorized stage C split across two thread groups.
// ---------------------------------------------------------------------------
#define RS_U 1156
#define RS_C 580

__global__ __launch_bounds__(512, 1) void k_route(
    const float* __restrict__ caps,  // [1024,8,1152]
    const float* __restrict__ W,     // [1152,8,16]
    const float* __restrict__ Wb,    // [1152,16]
    const float* __restrict__ ow,    // [10,10,16,1]
    const float* __restrict__ ob,    // [10]
    float* __restrict__ out)         // [1024,10]
{
    __shared__ __align__(16) float u[16 * RS_U];     // 73,984 B
    __shared__ __align__(16) float blog[10 * 1152];  // 46,080 B
    __shared__ __align__(16) float chalf[10 * RS_C]; // 23,200 B
    __shared__ float vv[160];
    __shared__ float ss[160], ss2[160];
    __shared__ float red[16];

    const int t = threadIdx.x;
    const int b = blockIdx.x;

    // ---- stage A: u[f][n], W loads 64B-coalesced via (n,fq) thread map ----
    {
        const int nl = t >> 2, fq = t & 3;
        for (int base = 0; base < 1152; base += 128) {
            int n = base + nl;
            float cv[8];
#pragma unroll
            for (int e = 0; e < 8; ++e) cv[e] = caps[(b * 8 + e) * 1152 + n];
            float4 a4 = ((const float4*)(Wb + n * 16))[fq];
#pragma unroll
            for (int e = 0; e < 8; ++e) {
                float4 w4 = ((const float4*)(W + n * 128 + e * 16))[fq];
                a4.x += cv[e] * w4.x; a4.y += cv[e] * w4.y;
                a4.z += cv[e] * w4.z; a4.w += cv[e] * w4.w;
            }
            u[(fq * 4 + 0) * RS_U + n] = a4.x;
            u[(fq * 4 + 1) * RS_U + n] = a4.y;
            u[(fq * 4 + 2) * RS_U + n] = a4.z;
            u[(fq * 4 + 3) * RS_U + n] = a4.w;
        }
    }
    {
        f32x4 z = {0.f, 0.f, 0.f, 0.f};
        for (int idx = t; idx < 2880; idx += 512) ((f32x4*)blog)[idx] = z;
    }
    __syncthreads();

    // stage-C group assignment: group0 = t<160 (m2 in [0,288)), group1 = 256<=t<416
    int cg = -1, cj = 0, cf = 0;
    if (t < 160) { cg = 0; cj = t >> 4; cf = t & 15; }
    else if (t >= 256 && t < 416) { cg = 1; cj = (t - 256) >> 4; cf = (t - 256) & 15; }

    for (int iter = 0; iter < 3; ++iter) {
        float sacc = 0.f;
        for (int h = 0; h < 2; ++h) {
            // ---- stage B: c = softmax_j(blog) for this half ----
            for (int idx = t; idx < 576; idx += 512) {
                int n = h * 576 + idx;
                float bv[10], m = -1e30f;
#pragma unroll
                for (int jj = 0; jj < 10; ++jj) {
                    bv[jj] = blog[jj * 1152 + n];
                    m = fmaxf(m, bv[jj]);
                }
                float sum = 0.f;
#pragma unroll
                for (int jj = 0; jj < 10; ++jj) { bv[jj] = __expf(bv[jj] - m); sum += bv[jj]; }
                float inv = 1.f / sum;
#pragma unroll
                for (int jj = 0; jj < 10; ++jj) chalf[jj * RS_C + idx] = bv[jj] * inv;
            }
            __syncthreads();
            // ---- stage C: s[j][f] partial over this (h, group) quarter ----
            if (cg >= 0) {
                const f32x4* crow = (const f32x4*)(chalf + cj * RS_C + cg * 288);
                const f32x4* urow = (const f32x4*)(u + cf * RS_U + h * 576 + cg * 288);
#pragma unroll 4
                for (int m2 = 0; m2 < 72; ++m2) {
                    f32x4 c4 = crow[m2], u4 = urow[m2];
                    sacc += c4.x * u4.x + c4.y * u4.y + c4.z * u4.z + c4.w * u4.w;
                }
            }
            __syncthreads();  // before next half overwrites chalf
        }
        if (cg == 0) ss[cj * 16 + cf] = sacc;
        else if (cg == 1) ss2[cj * 16 + cf] = sacc;
        __syncthreads();
        // ---- stage D: squash -> v[f][j] ----
        if (t < 16) {
            float sv[10], l2 = 0.f, l1 = 0.f;
#pragma unroll
            for (int jj = 0; jj < 10; ++jj) {
                sv[jj] = ss[jj * 16 + t] + ss2[jj * 16 + t];
                l2 += sv[jj] * sv[jj]; l1 += fabsf(sv[jj]);
            }
            l2 = sqrtf(l2);
            float scale = l2 / (1.f + l2) / l1;
#pragma unroll
            for (int jj = 0; jj < 10; ++jj) vv[t * 10 + jj] = sv[jj] * scale;
        }
        __syncthreads();
        // ---- stage E: blog[j][n] += sum_f u[f][n]*v[f][j] ----
        if (iter < 2) {
            for (int n = t; n < 1152; n += 512) {
                float a[10];
#pragma unroll
                for (int jj = 0; jj < 10; ++jj) a[jj] = 0.f;
#pragma unroll
                for (int ff = 0; ff < 16; ++ff) {
                    float uf = u[ff * RS_U + n];
#pragma unroll
                    for (int jj = 0; jj < 10; ++jj) a[jj] += uf * vv[ff * 10 + jj];
                }
#pragma unroll
                for (int jj = 0; jj < 10; ++jj) blog[jj * 1152 + n] += a[jj];
            }
        }
        __syncthreads();
    }

    // ---- output head + softmax ----
    if (t < 10) {
        float l = ob[t];
#pragma unroll
        for (int i2 = 0; i2 < 10; ++i2)
#pragma unroll
            for (int ff = 0; ff < 16; ++ff)
                l += vv[ff * 10 + i2] * ow[t * 160 + i2 * 16 + ff];
        red[t] = l;
    }
    __syncthreads();
    if (t == 0) {
        float m = -1e30f;
        for (int o = 0; o < 10; ++o) m = fmaxf(m, red[o]);
        float sum = 0.f; float e[10];
        for (int o = 0; o < 10; ++o) { e[o] = __expf(red[o] - m); sum += e[o]; }
        float inv = 1.f / sum;
        for (int o = 0; o < 10; ++o) out[b * 10 + o] = e[o] * inv;
    }
}

extern "C" void kernel_launch(void* const* d_in, const int* in_sizes, int n_in,
                              void* d_out, int out_size, void* d_ws, size_t ws_size,
                              hipStream_t stream) {
    const float* x     = (const float*)d_in[0];
    const float* c1w   = (const float*)d_in[1];
    const float* c1b   = (const float*)d_in[2];
    const float* pw    = (const float*)d_in[3];
    const float* pb    = (const float*)d_in[4];
    const float* digW  = (const float*)d_in[5];
    const float* digWb = (const float*)d_in[6];
    const float* outw  = (const float*)d_in[7];
    const float* outb  = (const float*)d_in[8];
    float* out = (float*)d_out;

    float* caps = (float*)d_ws;
    unsigned short* w1f = (unsigned short*)((char*)d_ws + CAPS_BYTES);
    unsigned short* w2f = w1f + A1F_ELEMS;

    k_prep<<<dim3(480), dim3(256), 0, stream>>>(c1w, pw, w1f, w2f);
    k_conv<<<dim3(4096), dim3(256), 0, stream>>>(x, c1b, pb, w1f, w2f, caps);
    k_route<<<dim3(1024), dim3(512), 0, stream>>>(caps, digW, digWb, outw, outb, out);
}

// Round 4
// 201.942 us; speedup vs baseline: 11.2966x; 1.7479x over previous
//
#include <hip/hip_runtime.h>
#include <math.h>

typedef __attribute__((ext_vector_type(8))) short bf16x8;
typedef __attribute__((ext_vector_type(4))) float f32x4;
#define MFMA16(a, b, c) __builtin_amdgcn_mfma_f32_16x16x32_bf16(a, b, c, 0, 0, 0)

union U8 { bf16x8 v; int i4[4]; };
union P4 { unsigned short h[4]; uint2 u2; };

__device__ __forceinline__ unsigned short f2bf(float x) {
    unsigned u = __builtin_bit_cast(unsigned, x);
    unsigned r = (u + 0x7fffu + ((u >> 16) & 1u)) >> 16;   // RNE
    return (unsigned short)r;
}

// conv1 K-permutation sigma (same on A and B, cancels):
// kidx = grp*8+e: grp 0..8 -> (ky=grp,kx=e); grp 9 -> (ky=e,kx=8); grp 10 e==0 -> (8,8); else pad
__device__ __forceinline__ int koff_of(int kidx) {
    int grp = kidx >> 3, e = kidx & 7;
    if (grp < 9)  return grp * 9 + e;
    if (grp == 9) return e * 9 + 8;
    if (grp == 10) return (e == 0) ? 80 : -1;
    return -1;
}

#define CAPS_BYTES 37748736
#define A1F_ELEMS  24576
#define W3F_ELEMS  82944   // 81 taps * 2 m * 64 lanes * 8 e

// ---------------------------------------------------------------------------
// K0: pack conv weights into MFMA fragment layout (bf16)
// ---------------------------------------------------------------------------
__global__ void k_prep(const float* __restrict__ c1w,  // [256,1,9,9]
                       const float* __restrict__ pw,   // [32,32,1,9,9]
                       unsigned short* __restrict__ w1f,
                       unsigned short* __restrict__ w3f)
{
    int idx = blockIdx.x * 256 + threadIdx.x;
    if (idx < A1F_ELEMS) {
        int e = idx & 7, lane = (idx >> 3) & 63, f = idx >> 9;
        int k3 = f % 3, m = (f / 3) & 1, d = f / 6;
        int ch = (lane & 15) + m * 16;
        int kidx = k3 * 32 + ((lane >> 4) << 3) + e;
        int ko = koff_of(kidx);
        w1f[idx] = f2bf(ko >= 0 ? c1w[(ch * 8 + d) * 81 + ko] : 0.f);
    } else if (idx < A1F_ELEMS + W3F_ELEMS) {
        int j = idx - A1F_ELEMS;
        int e = j & 7, lane = (j >> 3) & 63, f = j >> 9;
        int m = f & 1, tap = f >> 1;
        int oc = (lane & 15) + m * 16;
        int i = ((lane >> 4) << 3) + e;
        w3f[j] = f2bf(pw[oc * 2592 + i * 81 + tap]);
    }
}

// ---------------------------------------------------------------------------
// K1: fused conv1 + prim conv. One block = one (b,d) slice. 4 blocks/CU.
// interm layout: [pos 400][ch 40-stride] u16 -> phase-2 B-frag = 1 ds_read_b128
// ---------------------------------------------------------------------------
#define ICS 40   // interm channel stride (u16): 80 B, 16B-aligned, 20-word bank step

__global__ __launch_bounds__(256, 4) void k_conv(
    const float* __restrict__ x,    // [1024,1,28,28]
    const float* __restrict__ c1b,  // [256]
    const float* __restrict__ pb,   // [32]
    const unsigned short* __restrict__ w1f,
    const unsigned short* __restrict__ w3f,
    float* __restrict__ caps)       // [1024,8,1152]
{
    __shared__ __align__(16) unsigned short img[800];
    __shared__ __align__(16) unsigned short imgs[800];          // shifted by 1
    __shared__ __align__(16) unsigned short interm[400 * ICS];  // 32000 B; f32x4 overlay in epilogue

    const int t = threadIdx.x;
    const int lane = t & 63, w = t >> 6;
    const int g = lane >> 4, col = lane & 15;
    const int b = blockIdx.x >> 3, d = blockIdx.x & 7;

    // ---- stage image (bf16) + shifted copy ----
    for (int idx = t; idx < 784; idx += 256) {
        unsigned short v = f2bf(x[b * 784 + idx]);
        img[idx] = v;
        if (idx > 0) imgs[idx - 1] = v;
    }
    __syncthreads();

    // =================== phase 1: conv1 (25 tiles over 4 waves) ===================
    {
        bf16x8 a1[2][3];
        const bf16x8* w1p = (const bf16x8*)w1f;
#pragma unroll
        for (int m = 0; m < 2; ++m)
#pragma unroll
            for (int k3 = 0; k3 < 3; ++k3)
                a1[m][k3] = w1p[((d * 2 + m) * 3 + k3) * 64 + lane];

        float bias[2][4];
#pragma unroll
        for (int m = 0; m < 2; ++m)
#pragma unroll
            for (int r = 0; r < 4; ++r)
                bias[m][r] = c1b[(m * 16 + g * 4 + r) * 8 + d];

        for (int q = w; q < 25; q += 4) {
            int p = q * 16 + col;
            int py = p / 20, px = p - py * 20;
            int base = py * 28 + px;
            const unsigned short* rbase = (base & 1) ? &imgs[base - 1] : &img[base];

            bf16x8 bfrag[3];
#pragma unroll
            for (int k3 = 0; k3 < 2; ++k3) {
                int grp = k3 * 4 + g;
                U8 u8;
#pragma unroll
                for (int qq = 0; qq < 4; ++qq)
                    u8.i4[qq] = *(const int*)(rbase + grp * 28 + 2 * qq);
                bfrag[k3] = u8.v;
            }
            {
                U8 u8;
                if (g == 0) {
#pragma unroll
                    for (int qq = 0; qq < 4; ++qq)
                        u8.i4[qq] = *(const int*)(rbase + 8 * 28 + 2 * qq);
                } else if (g == 1) {
#pragma unroll
                    for (int e = 0; e < 8; ++e)
                        u8.v[e] = (short)img[base + e * 28 + 8];
                } else if (g == 2) {
                    u8.i4[0] = u8.i4[1] = u8.i4[2] = u8.i4[3] = 0;
                    u8.v[0] = (short)img[base + 8 * 28 + 8];
                } else {
                    u8.i4[0] = u8.i4[1] = u8.i4[2] = u8.i4[3] = 0;
                }
                bfrag[2] = u8.v;
            }

            f32x4 acc0 = {0.f, 0.f, 0.f, 0.f};
            f32x4 acc1 = {0.f, 0.f, 0.f, 0.f};
#pragma unroll
            for (int k3 = 0; k3 < 3; ++k3) {
                acc0 = MFMA16(a1[0][k3], bfrag[k3], acc0);
                acc1 = MFMA16(a1[1][k3], bfrag[k3], acc1);
            }
            // write channel-interleaved: interm[p][ch], ch blocks g*4 and 16+g*4
            P4 pk0, pk1;
#pragma unroll
            for (int r = 0; r < 4; ++r) {
                pk0.h[r] = f2bf(fmaxf(acc0[r] + bias[0][r], 0.f));
                pk1.h[r] = f2bf(fmaxf(acc1[r] + bias[1][r], 0.f));
            }
            *(uint2*)(&interm[p * ICS + g * 4])      = pk0.u2;
            *(uint2*)(&interm[p * ICS + 16 + g * 4]) = pk1.u2;
        }
    }
    __syncthreads();

    // =================== phase 2: prim conv, tap-split by wave ===================
    f32x4 acc[2][3];
#pragma unroll
    for (int m = 0; m < 2; ++m)
#pragma unroll
        for (int nt = 0; nt < 3; ++nt)
            acc[m][nt] = (f32x4){0.f, 0.f, 0.f, 0.f};
    {
        int base2[3];   // (2*yh)*20 + 2*xw for valid p2, else 0
#pragma unroll
        for (int nt = 0; nt < 3; ++nt) {
            int p2 = nt * 16 + col;
            int xw = p2 / 6, yh = p2 - xw * 6;
            base2[nt] = (p2 < 36) ? (yh * 40 + xw * 2) : 0;
        }
        const bf16x8* w3p = (const bf16x8*)w3f;
        int ky = 0, kx = w;
        for (int tap = w; tap < 81; tap += 4) {
            bf16x8 a0 = w3p[(tap * 2 + 0) * 64 + lane];
            bf16x8 a1v = w3p[(tap * 2 + 1) * 64 + lane];
            int koff = ky * 20 + kx;
#pragma unroll
            for (int nt = 0; nt < 3; ++nt) {
                int pos = base2[nt] + koff;
                bf16x8 bfrag = *(const bf16x8*)(&interm[pos * ICS + g * 8]);
                acc[0][nt] = MFMA16(a0, bfrag, acc[0][nt]);
                acc[1][nt] = MFMA16(a1v, bfrag, acc[1][nt]);
            }
            kx += 4;
            if (kx >= 9) { kx -= 9; ++ky; }
        }
    }
    __syncthreads();                 // interm reads done
    // ---- cross-wave reduction (f32x4 overlay on interm) ----
    f32x4* rp = (f32x4*)&interm[0];  // 4 waves * 6 tiles * 64 lanes = 24576 B
    {
#pragma unroll
        for (int m = 0; m < 2; ++m)
#pragma unroll
            for (int nt = 0; nt < 3; ++nt)
                rp[(w * 6 + m * 3 + nt) * 64 + lane] = acc[m][nt];
    }
    __syncthreads();
    for (int idx = t; idx < 384; idx += 256) {
        int tile = idx >> 6, ls = idx & 63;
        f32x4 s = rp[tile * 64 + ls];
#pragma unroll
        for (int ww = 1; ww < 4; ++ww)
            s += rp[(ww * 6 + tile) * 64 + ls];
        int m = tile / 3, nt = tile - m * 3;
        int p2 = nt * 16 + (ls & 15);
        if (p2 < 36) {
            int gr = ls >> 4;
#pragma unroll
            for (int r = 0; r < 4; ++r) {
                int oc = m * 16 + gr * 4 + r;
                caps[(b * 8 + d) * 1152 + oc * 36 + p2] = fmaxf(s[r] + pb[oc], 0.f);
            }
        }
    }
}

// ---------------------------------------------------------------------------
// K2: routing. 576 threads; blog in registers (thread owns n=2t,2t+1);
// stage C 2x2-register-blocked dot over all threads.
// ---------------------------------------------------------------------------
#define UST 1156
#define CST 1164

__global__ __launch_bounds__(576) void k_route(
    const float* __restrict__ caps,  // [1024,8,1152]
    const float* __restrict__ W,     // [1152,8,16]
    const float* __restrict__ Wb,    // [1152,16]
    const float* __restrict__ ow,    // [10,10,16,1]
    const float* __restrict__ ob,    // [10]
    float* __restrict__ out)         // [1024,10]
{
    __shared__ __align__(16) float u[16 * UST];   // 73,984 B  u[f][n]
    __shared__ __align__(16) float c[10 * CST];   // 46,560 B  c[j][n]
    __shared__ __align__(16) float sred[14 * 160];// 8,960 B
    __shared__ __align__(16) float vv[16 * 12];   // v[f][j], stride 12 for aligned f32x4
    __shared__ float ss[160];
    __shared__ float red2[16];

    const int t = threadIdx.x;
    const int b = blockIdx.x;
    const int n0 = 2 * t;

    // ---- stage A: u[f][n] ----
    {
        const int nl = t >> 2, fq = t & 3;
        for (int base = 0; base < 1152; base += 144) {
            int n = base + nl;
            float cv[8];
#pragma unroll
            for (int e = 0; e < 8; ++e) cv[e] = caps[(b * 8 + e) * 1152 + n];
            float4 a4 = ((const float4*)(Wb + n * 16))[fq];
#pragma unroll
            for (int e = 0; e < 8; ++e) {
                float4 w4 = ((const float4*)(W + n * 128 + e * 16))[fq];
                a4.x += cv[e] * w4.x; a4.y += cv[e] * w4.y;
                a4.z += cv[e] * w4.z; a4.w += cv[e] * w4.w;
            }
            u[(fq * 4 + 0) * UST + n] = a4.x;
            u[(fq * 4 + 1) * UST + n] = a4.y;
            u[(fq * 4 + 2) * UST + n] = a4.z;
            u[(fq * 4 + 3) * UST + n] = a4.w;
        }
    }
    float breg[2][10];
#pragma unroll
    for (int s = 0; s < 2; ++s)
#pragma unroll
        for (int jj = 0; jj < 10; ++jj) breg[s][jj] = 0.f;
    __syncthreads();

    // stage C decomposition: chunk = t/40 (14 chunks of K), tile = t%40 = (jp,fp)
    const int chunk = t / 40, tile = t - chunk * 40;
    const int jp = tile >> 3, fp = tile & 7;
    const bool cact = (chunk < 14);
    const int nbase = chunk * 84;
    const int quads = (chunk == 13) ? 15 : 21;

    for (int iter = 0; iter < 3; ++iter) {
        // ---- stage B: thread-local softmax over j for n0, n0+1 -> c ----
        {
            float cv2[2][10];
#pragma unroll
            for (int s = 0; s < 2; ++s) {
                float m = breg[s][0];
#pragma unroll
                for (int jj = 1; jj < 10; ++jj) m = fmaxf(m, breg[s][jj]);
                float sum = 0.f;
#pragma unroll
                for (int jj = 0; jj < 10; ++jj) { cv2[s][jj] = __expf(breg[s][jj] - m); sum += cv2[s][jj]; }
                float inv = 1.f / sum;
#pragma unroll
                for (int jj = 0; jj < 10; ++jj) cv2[s][jj] *= inv;
            }
#pragma unroll
            for (int jj = 0; jj < 10; ++jj)
                *(float2*)(&c[jj * CST + n0]) = make_float2(cv2[0][jj], cv2[1][jj]);
        }
        __syncthreads();
        // ---- stage C: s[j][f] via 2x2-blocked dots ----
        if (cact) {
            const f32x4* c0 = (const f32x4*)(c + (2 * jp) * CST + nbase);
            const f32x4* c1 = (const f32x4*)(c + (2 * jp + 1) * CST + nbase);
            const f32x4* u0 = (const f32x4*)(u + (2 * fp) * UST + nbase);
            const f32x4* u1 = (const f32x4*)(u + (2 * fp + 1) * UST + nbase);
            f32x4 a00 = {0,0,0,0}, a01 = {0,0,0,0}, a10 = {0,0,0,0}, a11 = {0,0,0,0};
            for (int q = 0; q < quads; ++q) {
                f32x4 x0 = c0[q], x1 = c1[q], y0 = u0[q], y1 = u1[q];
                a00 += x0 * y0; a01 += x0 * y1;
                a10 += x1 * y0; a11 += x1 * y1;
            }
            f32x4 pk;
            pk.x = a00.x + a00.y + a00.z + a00.w;
            pk.y = a01.x + a01.y + a01.z + a01.w;
            pk.z = a10.x + a10.y + a10.z + a10.w;
            pk.w = a11.x + a11.y + a11.z + a11.w;
            *(f32x4*)(&sred[t * 4]) = pk;   // [(chunk*40+tile)*4 + r*2+c]
        }
        __syncthreads();
        // ---- reduce partials + squash ----
        if (t < 160) {
            int j = t >> 4, f = t & 15;
            int idx0 = ((j >> 1) * 8 + (f >> 1)) * 4 + (j & 1) * 2 + (f & 1);
            float s = 0.f;
#pragma unroll
            for (int ch = 0; ch < 14; ++ch) s += sred[ch * 160 + idx0];
            ss[j * 16 + f] = s;
        }
        __syncthreads();
        if (t < 16) {
            float sv[10], l2 = 0.f, l1 = 0.f;
#pragma unroll
            for (int jj = 0; jj < 10; ++jj) {
                sv[jj] = ss[jj * 16 + t];
                l2 += sv[jj] * sv[jj]; l1 += fabsf(sv[jj]);
            }
            l2 = sqrtf(l2);
            float scale = l2 / (1.f + l2) / l1;
#pragma unroll
            for (int jj = 0; jj < 10; ++jj) vv[t * 12 + jj] = sv[jj] * scale;
        }
        __syncthreads();
        // ---- stage E: breg[s][j] += sum_f u[f][n0+s] * v[f][j] (register-local) ----
        if (iter < 2) {
#pragma unroll
            for (int f = 0; f < 16; ++f) {
                float2 uf = *(const float2*)(&u[f * UST + n0]);
                f32x4 v0 = *(const f32x4*)(&vv[f * 12]);
                f32x4 v1 = *(const f32x4*)(&vv[f * 12 + 4]);
                float2 v2 = *(const float2*)(&vv[f * 12 + 8]);
                breg[0][0] += uf.x * v0.x; breg[1][0] += uf.y * v0.x;
                breg[0][1] += uf.x * v0.y; breg[1][1] += uf.y * v0.y;
                breg[0][2] += uf.x * v0.z; breg[1][2] += uf.y * v0.z;
                breg[0][3] += uf.x * v0.w; breg[1][3] += uf.y * v0.w;
                breg[0][4] += uf.x * v1.x; breg[1][4] += uf.y * v1.x;
                breg[0][5] += uf.x * v1.y; breg[1][5] += uf.y * v1.y;
                breg[0][6] += uf.x * v1.z; breg[1][6] += uf.y * v1.z;
                breg[0][7] += uf.x * v1.w; breg[1][7] += uf.y * v1.w;
                breg[0][8] += uf.x * v2.x; breg[1][8] += uf.y * v2.x;
                breg[0][9] += uf.x * v2.y; breg[1][9] += uf.y * v2.y;
            }
        }
        __syncthreads();
    }

    // ---- output head + softmax ----
    if (t < 10) {
        float l = ob[t];
#pragma unroll
        for (int i2 = 0; i2 < 10; ++i2)
#pragma unroll
            for (int ff = 0; ff < 16; ++ff)
                l += vv[ff * 12 + i2] * ow[t * 160 + i2 * 16 + ff];
        red2[t] = l;
    }
    __syncthreads();
    if (t == 0) {
        float m = -1e30f;
        for (int o = 0; o < 10; ++o) m = fmaxf(m, red2[o]);
        float sum = 0.f; float e[10];
        for (int o = 0; o < 10; ++o) { e[o] = __expf(red2[o] - m); sum += e[o]; }
        float inv = 1.f / sum;
        for (int o = 0; o < 10; ++o) out[b * 10 + o] = e[o] * inv;
    }
}

extern "C" void kernel_launch(void* const* d_in, const int* in_sizes, int n_in,
                              void* d_out, int out_size, void* d_ws, size_t ws_size,
                              hipStream_t stream) {
    const float* x     = (const float*)d_in[0];
    const float* c1w   = (const float*)d_in[1];
    const float* c1b   = (const float*)d_in[2];
    const float* pw    = (const float*)d_in[3];
    const float* pb    = (const float*)d_in[4];
    const float* digW  = (const float*)d_in[5];
    const float* digWb = (const float*)d_in[6];
    const float* outw  = (const float*)d_in[7];
    const float* outb  = (const float*)d_in[8];
    float* out = (float*)d_out;

    float* caps = (float*)d_ws;
    unsigned short* w1f = (unsigned short*)((char*)d_ws + CAPS_BYTES);
    unsigned short* w3f = w1f + A1F_ELEMS;

    k_prep<<<dim3(420), dim3(256), 0, stream>>>(c1w, pw, w1f, w3f);
    k_conv<<<dim3(8192), dim3(256), 0, stream>>>(x, c1b, pb, w1f, w3f, caps);
    k_route<<<dim3(1024), dim3(576), 0, stream>>>(caps, digW, digWb, outw, outb, out);
}

// Round 5
// 187.660 us; speedup vs baseline: 12.1564x; 1.0761x over previous
//
#include <hip/hip_runtime.h>
#include <math.h>

typedef __attribute__((ext_vector_type(8))) short bf16x8;
typedef __attribute__((ext_vector_type(4))) float f32x4;
#define MFMA16(a, b, c) __builtin_amdgcn_mfma_f32_16x16x32_bf16(a, b, c, 0, 0, 0)

union U8 { bf16x8 v; int i4[4]; };
union P4 { unsigned short h[4]; uint2 u2; };

__device__ __forceinline__ unsigned short f2bf(float x) {
    unsigned u = __builtin_bit_cast(unsigned, x);
    unsigned r = (u + 0x7fffu + ((u >> 16) & 1u)) >> 16;   // RNE
    return (unsigned short)r;
}

// conv1 K-permutation sigma (same on A and B, cancels):
__device__ __forceinline__ int koff_of(int kidx) {
    int grp = kidx >> 3, e = kidx & 7;
    if (grp < 9)  return grp * 9 + e;
    if (grp == 9) return e * 9 + 8;
    if (grp == 10) return (e == 0) ? 80 : -1;
    return -1;
}

#define CAPS_BYTES 37748736
#define A1F_ELEMS  24576
#define W3F_ELEMS  82944   // 81 taps * 2 m * 64 lanes * 8 e

// LDS XOR swizzle: permutes 16B blocks within 128B windows; bits<4 untouched.
#define SWZ(A) ((A) ^ ((((A) >> 7) & 7) << 4))

// ---------------------------------------------------------------------------
// K0: pack conv weights into MFMA fragment layout (bf16)
// ---------------------------------------------------------------------------
__global__ void k_prep(const float* __restrict__ c1w,  // [256,1,9,9]
                       const float* __restrict__ pw,   // [32,32,1,9,9]
                       unsigned short* __restrict__ w1f,
                       unsigned short* __restrict__ w3f)
{
    int idx = blockIdx.x * 256 + threadIdx.x;
    if (idx < A1F_ELEMS) {
        int e = idx & 7, lane = (idx >> 3) & 63, f = idx >> 9;
        int k3 = f % 3, m = (f / 3) & 1, d = f / 6;
        int ch = (lane & 15) + m * 16;
        int kidx = k3 * 32 + ((lane >> 4) << 3) + e;
        int ko = koff_of(kidx);
        w1f[idx] = f2bf(ko >= 0 ? c1w[(ch * 8 + d) * 81 + ko] : 0.f);
    } else if (idx < A1F_ELEMS + W3F_ELEMS) {
        int j = idx - A1F_ELEMS;
        int e = j & 7, lane = (j >> 3) & 63, f = j >> 9;
        int m = f & 1, tap = f >> 1;
        int oc = (lane & 15) + m * 16;
        int i = ((lane >> 4) << 3) + e;
        w3f[j] = f2bf(pw[oc * 2592 + i * 81 + tap]);
    }
}

// ---------------------------------------------------------------------------
// K1: fused conv1 + prim conv. One block = one (b,d) slice. 4 blocks/CU.
// interm: [pos 400][ch 40-stride] u16, XOR-swizzled 16B blocks (SWZ).
// ---------------------------------------------------------------------------
#define ICS 40

__global__ __launch_bounds__(256, 4) void k_conv(
    const float* __restrict__ x,    // [1024,1,28,28]
    const float* __restrict__ c1b,  // [256]
    const float* __restrict__ pb,   // [32]
    const unsigned short* __restrict__ w1f,
    const unsigned short* __restrict__ w3f,
    float* __restrict__ caps)       // [1024,8,1152]
{
    __shared__ __align__(16) unsigned short img[800];
    __shared__ __align__(16) unsigned short imgs[800];          // shifted by 1
    __shared__ __align__(128) unsigned short interm[400 * ICS]; // 32000 B

    const int t = threadIdx.x;
    const int lane = t & 63, w = t >> 6;
    const int g = lane >> 4, col = lane & 15;
    const int b = blockIdx.x >> 3, d = blockIdx.x & 7;

    for (int idx = t; idx < 784; idx += 256) {
        unsigned short v = f2bf(x[b * 784 + idx]);
        img[idx] = v;
        if (idx > 0) imgs[idx - 1] = v;
    }
    __syncthreads();

    // =================== phase 1: conv1 ===================
    {
        bf16x8 a1[2][3];
        const bf16x8* w1p = (const bf16x8*)w1f;
#pragma unroll
        for (int m = 0; m < 2; ++m)
#pragma unroll
            for (int k3 = 0; k3 < 3; ++k3)
                a1[m][k3] = w1p[((d * 2 + m) * 3 + k3) * 64 + lane];

        float bias[2][4];
#pragma unroll
        for (int m = 0; m < 2; ++m)
#pragma unroll
            for (int r = 0; r < 4; ++r)
                bias[m][r] = c1b[(m * 16 + g * 4 + r) * 8 + d];

        for (int q = w; q < 25; q += 4) {
            int p = q * 16 + col;
            int py = p / 20, px = p - py * 20;
            int base = py * 28 + px;
            const unsigned short* rbase = (base & 1) ? &imgs[base - 1] : &img[base];

            bf16x8 bfrag[3];
#pragma unroll
            for (int k3 = 0; k3 < 2; ++k3) {
                int grp = k3 * 4 + g;
                U8 u8;
#pragma unroll
                for (int qq = 0; qq < 4; ++qq)
                    u8.i4[qq] = *(const int*)(rbase + grp * 28 + 2 * qq);
                bfrag[k3] = u8.v;
            }
            {
                U8 u8;
                if (g == 0) {
#pragma unroll
                    for (int qq = 0; qq < 4; ++qq)
                        u8.i4[qq] = *(const int*)(rbase + 8 * 28 + 2 * qq);
                } else if (g == 1) {
#pragma unroll
                    for (int e = 0; e < 8; ++e)
                        u8.v[e] = (short)img[base + e * 28 + 8];
                } else if (g == 2) {
                    u8.i4[0] = u8.i4[1] = u8.i4[2] = u8.i4[3] = 0;
                    u8.v[0] = (short)img[base + 8 * 28 + 8];
                } else {
                    u8.i4[0] = u8.i4[1] = u8.i4[2] = u8.i4[3] = 0;
                }
                bfrag[2] = u8.v;
            }

            f32x4 acc0 = {0.f, 0.f, 0.f, 0.f};
            f32x4 acc1 = {0.f, 0.f, 0.f, 0.f};
#pragma unroll
            for (int k3 = 0; k3 < 3; ++k3) {
                acc0 = MFMA16(a1[0][k3], bfrag[k3], acc0);
                acc1 = MFMA16(a1[1][k3], bfrag[k3], acc1);
            }
            P4 pk0, pk1;
#pragma unroll
            for (int r = 0; r < 4; ++r) {
                pk0.h[r] = f2bf(fmaxf(acc0[r] + bias[0][r], 0.f));
                pk1.h[r] = f2bf(fmaxf(acc1[r] + bias[1][r], 0.f));
            }
            int A0 = p * 80 + g * 8;
            int A1 = A0 + 32;
            *(uint2*)((char*)interm + SWZ(A0)) = pk0.u2;
            *(uint2*)((char*)interm + SWZ(A1)) = pk1.u2;
        }
    }
    __syncthreads();

    // =================== phase 2: prim conv, tap-split by wave ===================
    f32x4 acc[2][3];
#pragma unroll
    for (int m = 0; m < 2; ++m)
#pragma unroll
        for (int nt = 0; nt < 3; ++nt)
            acc[m][nt] = (f32x4){0.f, 0.f, 0.f, 0.f};
    {
        int abase[3];   // byte base per nt: pos0*80 + g*16
#pragma unroll
        for (int nt = 0; nt < 3; ++nt) {
            int p2 = nt * 16 + col;
            int xw = p2 / 6, yh = p2 - xw * 6;
            int pos0 = (p2 < 36) ? (yh * 40 + xw * 2) : 0;
            abase[nt] = pos0 * 80 + g * 16;
        }
        const bf16x8* w3p = (const bf16x8*)w3f;
        int ky = 0, kx = w;
        for (int tap = w; tap < 81; tap += 4) {
            bf16x8 a0 = w3p[(tap * 2 + 0) * 64 + lane];
            bf16x8 a1v = w3p[(tap * 2 + 1) * 64 + lane];
            int koff80 = (ky * 20 + kx) * 80;
#pragma unroll
            for (int nt = 0; nt < 3; ++nt) {
                int A = abase[nt] + koff80;
                bf16x8 bfrag = *(const bf16x8*)((const char*)interm + SWZ(A));
                acc[0][nt] = MFMA16(a0, bfrag, acc[0][nt]);
                acc[1][nt] = MFMA16(a1v, bfrag, acc[1][nt]);
            }
            kx += 4;
            if (kx >= 9) { kx -= 9; ++ky; }
        }
    }
    __syncthreads();
    // ---- cross-wave reduction (plain f32x4 overlay, no swizzle) ----
    f32x4* rp = (f32x4*)&interm[0];
    {
#pragma unroll
        for (int m = 0; m < 2; ++m)
#pragma unroll
            for (int nt = 0; nt < 3; ++nt)
                rp[(w * 6 + m * 3 + nt) * 64 + lane] = acc[m][nt];
    }
    __syncthreads();
    for (int idx = t; idx < 384; idx += 256) {
        int tile = idx >> 6, ls = idx & 63;
        f32x4 s = rp[tile * 64 + ls];
#pragma unroll
        for (int ww = 1; ww < 4; ++ww)
            s += rp[(ww * 6 + tile) * 64 + ls];
        int m = tile / 3, nt = tile - m * 3;
        int p2 = nt * 16 + (ls & 15);
        if (p2 < 36) {
            int gr = ls >> 4;
#pragma unroll
            for (int r = 0; r < 4; ++r) {
                int oc = m * 16 + gr * 4 + r;
                caps[(b * 8 + d) * 1152 + oc * 36 + p2] = fmaxf(s[r] + pb[oc], 0.f);
            }
        }
    }
}

// ---------------------------------------------------------------------------
// K2: routing. 576 threads (9 waves). u,c in bf16; stage C via MFMA;
// blog in registers. LDS ~71 KB -> 2 blocks/CU.
// ---------------------------------------------------------------------------
#define USB 1160   // u_bf row stride (bf16)
#define CSB 1160   // c_bf row stride

__global__ __launch_bounds__(576, 5) void k_route(
    const float* __restrict__ caps,  // [1024,8,1152]
    const float* __restrict__ W,     // [1152,8,16]
    const float* __restrict__ Wb,    // [1152,16]
    const float* __restrict__ ow,    // [10,10,16,1]
    const float* __restrict__ ob,    // [10]
    float* __restrict__ out)         // [1024,10]
{
    __shared__ __align__(16) unsigned short u_bf[16 * USB];  // 37,120 B  u[f][n]
    __shared__ __align__(16) unsigned short c_bf[10 * CSB];  // 23,200 B  c[j][n]
    __shared__ __align__(16) float sred[9 * 256];            //  9,216 B
    __shared__ __align__(16) float vv[16 * 12];
    __shared__ float ss[160];
    __shared__ float red2[16];

    const int t = threadIdx.x;
    const int lane = t & 63, wv = t >> 6;
    const int g = lane >> 4, col = lane & 15;
    const int b = blockIdx.x;
    const int n0 = 2 * t;

    // ---- stage A: u[f][n] -> bf16 ----
    {
        const int nl = t >> 2, fq = t & 3;
        for (int base = 0; base < 1152; base += 144) {
            int n = base + nl;
            float cv[8];
#pragma unroll
            for (int e = 0; e < 8; ++e) cv[e] = caps[(b * 8 + e) * 1152 + n];
            float4 a4 = ((const float4*)(Wb + n * 16))[fq];
#pragma unroll
            for (int e = 0; e < 8; ++e) {
                float4 w4 = ((const float4*)(W + n * 128 + e * 16))[fq];
                a4.x += cv[e] * w4.x; a4.y += cv[e] * w4.y;
                a4.z += cv[e] * w4.z; a4.w += cv[e] * w4.w;
            }
            u_bf[(fq * 4 + 0) * USB + n] = f2bf(a4.x);
            u_bf[(fq * 4 + 1) * USB + n] = f2bf(a4.y);
            u_bf[(fq * 4 + 2) * USB + n] = f2bf(a4.z);
            u_bf[(fq * 4 + 3) * USB + n] = f2bf(a4.w);
        }
    }
    float breg[2][10];
#pragma unroll
    for (int s = 0; s < 2; ++s)
#pragma unroll
        for (int jj = 0; jj < 10; ++jj) breg[s][jj] = 0.f;
    __syncthreads();

    const int jrow = (col < 10) ? col : 9;   // A-frag row clamp (rows 10-15 unused)

    for (int iter = 0; iter < 3; ++iter) {
        // ---- stage B: thread-local softmax -> c_bf (2 n's packed per b32) ----
        {
            float cv2[2][10];
#pragma unroll
            for (int s = 0; s < 2; ++s) {
                float m = breg[s][0];
#pragma unroll
                for (int jj = 1; jj < 10; ++jj) m = fmaxf(m, breg[s][jj]);
                float sum = 0.f;
#pragma unroll
                for (int jj = 0; jj < 10; ++jj) { cv2[s][jj] = __expf(breg[s][jj] - m); sum += cv2[s][jj]; }
                float inv = 1.f / sum;
#pragma unroll
                for (int jj = 0; jj < 10; ++jj) cv2[s][jj] *= inv;
            }
#pragma unroll
            for (int jj = 0; jj < 10; ++jj) {
                unsigned pk = (unsigned)f2bf(cv2[0][jj]) | ((unsigned)f2bf(cv2[1][jj]) << 16);
                *(unsigned*)(&c_bf[jj * CSB + n0]) = pk;
            }
        }
        __syncthreads();
        // ---- stage C: s[j][f] via MFMA, wave wv owns n-chunk [wv*128, +128) ----
        {
            f32x4 sp = {0.f, 0.f, 0.f, 0.f};
#pragma unroll
            for (int mf = 0; mf < 4; ++mf) {
                int nk = wv * 128 + mf * 32 + g * 8;
                bf16x8 af = *(const bf16x8*)(&c_bf[jrow * CSB + nk]);
                bf16x8 bf = *(const bf16x8*)(&u_bf[col * USB + nk]);
                sp = MFMA16(af, bf, sp);
            }
            *(f32x4*)(&sred[wv * 256 + lane * 4]) = sp;
        }
        __syncthreads();
        // ---- reduce 9 wave-partials -> ss[j][f] ----
        if (t < 160) {
            int j = t >> 4, f = t & 15;
            int li = ((j >> 2) * 16 + f) * 4 + (j & 3);
            float s = 0.f;
#pragma unroll
            for (int ww = 0; ww < 9; ++ww) s += sred[ww * 256 + li];
            ss[j * 16 + f] = s;
        }
        __syncthreads();
        // ---- squash -> vv[f][j] ----
        if (t < 16) {
            float sv[10], l2 = 0.f, l1 = 0.f;
#pragma unroll
            for (int jj = 0; jj < 10; ++jj) {
                sv[jj] = ss[jj * 16 + t];
                l2 += sv[jj] * sv[jj]; l1 += fabsf(sv[jj]);
            }
            l2 = sqrtf(l2);
            float scale = l2 / (1.f + l2) / l1;
#pragma unroll
            for (int jj = 0; jj < 10; ++jj) vv[t * 12 + jj] = sv[jj] * scale;
        }
        __syncthreads();
        // ---- stage E: breg[s][j] += sum_f u_bf[f][n0+s] * vv[f][j] ----
        if (iter < 2) {
#pragma unroll
            for (int f = 0; f < 16; ++f) {
                unsigned pair = *(const unsigned*)(&u_bf[f * USB + n0]);
                float ux = __builtin_bit_cast(float, pair << 16);
                float uy = __builtin_bit_cast(float, pair & 0xffff0000u);
                f32x4 v0 = *(const f32x4*)(&vv[f * 12]);
                f32x4 v1 = *(const f32x4*)(&vv[f * 12 + 4]);
                float2 v2 = *(const float2*)(&vv[f * 12 + 8]);
                breg[0][0] += ux * v0.x; breg[1][0] += uy * v0.x;
                breg[0][1] += ux * v0.y; breg[1][1] += uy * v0.y;
                breg[0][2] += ux * v0.z; breg[1][2] += uy * v0.z;
                breg[0][3] += ux * v0.w; breg[1][3] += uy * v0.w;
                breg[0][4] += ux * v1.x; breg[1][4] += uy * v1.x;
                breg[0][5] += ux * v1.y; breg[1][5] += uy * v1.y;
                breg[0][6] += ux * v1.z; breg[1][6] += uy * v1.z;
                breg[0][7] += ux * v1.w; breg[1][7] += uy * v1.w;
                breg[0][8] += ux * v2.x; breg[1][8] += uy * v2.x;
                breg[0][9] += ux * v2.y; breg[1][9] += uy * v2.y;
            }
        }
        __syncthreads();
    }

    // ---- output head + softmax ----
    if (t < 10) {
        float l = ob[t];
#pragma unroll
        for (int i2 = 0; i2 < 10; ++i2)
#pragma unroll
            for (int ff = 0; ff < 16; ++ff)
                l += vv[ff * 12 + i2] * ow[t * 160 + i2 * 16 + ff];
        red2[t] = l;
    }
    __syncthreads();
    if (t == 0) {
        float m = -1e30f;
        for (int o = 0; o < 10; ++o) m = fmaxf(m, red2[o]);
        float sum = 0.f; float e[10];
        for (int o = 0; o < 10; ++o) { e[o] = __expf(red2[o] - m); sum += e[o]; }
        float inv = 1.f / sum;
        for (int o = 0; o < 10; ++o) out[b * 10 + o] = e[o] * inv;
    }
}

extern "C" void kernel_launch(void* const* d_in, const int* in_sizes, int n_in,
                              void* d_out, int out_size, void* d_ws, size_t ws_size,
                              hipStream_t stream) {
    const float* x     = (const float*)d_in[0];
    const float* c1w   = (const float*)d_in[1];
    const float* c1b   = (const float*)d_in[2];
    const float* pw    = (const float*)d_in[3];
    const float* pb    = (const float*)d_in[4];
    const float* digW  = (const float*)d_in[5];
    const float* digWb = (const float*)d_in[6];
    const float* outw  = (const float*)d_in[7];
    const float* outb  = (const float*)d_in[8];
    float* out = (float*)d_out;

    float* caps = (float*)d_ws;
    unsigned short* w1f = (unsigned short*)((char*)d_ws + CAPS_BYTES);
    unsigned short* w3f = w1f + A1F_ELEMS;

    k_prep<<<dim3(420), dim3(256), 0, stream>>>(c1w, pw, w1f, w3f);
    k_conv<<<dim3(8192), dim3(256), 0, stream>>>(x, c1b, pb, w1f, w3f, caps);
    k_route<<<dim3(1024), dim3(576), 0, stream>>>(caps, digW, digWb, outw, outb, out);
}